// Round 11
// baseline (1876.031 us; speedup 1.0000x reference)
//
#include <hip/hip_runtime.h>
#include <hip/hip_bf16.h>

// Spiking transformer block (Spikformer SSA) on MI355X.
// Layout: [channel][m], m = (b*196+n)*4 + t (time innermost).
//
// v-branch flavor ledger vs np ref: in-order FMA (r4) FAIL; scalar no-FMA
// (r7) FAIL; fp64 (r8) FAIL; 8-stripe+96-block pairwise (r9) FAIL; in-order
// FMA + unfused BN (r10) FAIL. BLAS-per-element == in-order FMA -> excluded.
// Remaining: numpy einsum optimize=False SOP "contig_outstride0_two":
// c innermost (buffered contig), BASELINE SSE2 SIMD: 4 lanes (lane = c%4),
// separate mul+add (no FMA at SSE2 baseline), horizontal reduce
// (L0+L2)+(L1+L3), then unfused fp32 BN/LIF ufuncs. This round emulates
// that exactly (v only); out0 path stays the five-times-proven r4 pipeline.

#define Cv 384
#define Nv 196
#define Mv 25088        // 128*196 columns
#define HIDv 1536
#define Bv 32
#define Zv 6272         // z = b*196+n
#define TBv 128
#define CHUNK 12544     // Mv/2
#define UC 3136         // per-chunk u

// ---- transpose: xp[c*Mv + (b*196+n)*4 + t] = x[((t*32+b)*384+c)*196+n] ----
__global__ __launch_bounds__(256) void k_transpose_in(const float* __restrict__ x,
                                                      float* __restrict__ xp)
{
    int idx = blockIdx.x * 256 + threadIdx.x;
    int c   = idx / Mv;
    int rem = idx - c * Mv;
    int z = rem >> 2, t = rem & 3;
    int b = z / Nv, n = z - b * Nv;
    xp[idx] = x[((size_t)(t * Bv + b) * Cv + c) * Nv + n];
}

// ---- fp32 GEMM (in-order FMA; out0 path, proven r4/r7/r8/r9/r10) -----------
__global__ __launch_bounds__(256) void k_gemm(const float* __restrict__ W,
                                              const float* __restrict__ X,
                                              float* __restrict__ Y,
                                              int K, int ldx, int ldy,
                                              const float* __restrict__ bias,
                                              int cb)
{
    __shared__ float sW[8][128];
    __shared__ float sX[8][64];
    int ym0 = blockIdx.x * 64;
    int m0  = cb + ym0;
    int o0  = blockIdx.y * 128;
    int tid = threadIdx.x;
    int wo = tid & 127, wh = tid >> 7;
    int xr = tid >> 5,  xc = (tid & 31) * 2;
    int to = tid >> 4,  tm = tid & 15;

    const float* Wp = W + (size_t)(o0 + wo) * K + wh * 4;
    const float* Xp = X + (size_t)xr * ldx + m0 + xc;

    float acc[8][4] = {};
    for (int k0 = 0; k0 < K; k0 += 8) {
        float4 w4 = *(const float4*)(Wp + k0);
        float2 x2 = *(const float2*)(Xp + (size_t)k0 * ldx);
        __syncthreads();
        sW[wh*4+0][wo] = w4.x;
        sW[wh*4+1][wo] = w4.y;
        sW[wh*4+2][wo] = w4.z;
        sW[wh*4+3][wo] = w4.w;
        *(float2*)&sX[xr][xc] = x2;
        __syncthreads();
        #pragma unroll
        for (int kk = 0; kk < 8; ++kk) {
            float4 a0 = *(const float4*)&sW[kk][to*8];
            float4 a1 = *(const float4*)&sW[kk][to*8+4];
            float4 bb = *(const float4*)&sX[kk][tm*4];
            float av[8] = {a0.x,a0.y,a0.z,a0.w,a1.x,a1.y,a1.z,a1.w};
            float bv[4] = {bb.x,bb.y,bb.z,bb.w};
            #pragma unroll
            for (int i = 0; i < 8; ++i)
                #pragma unroll
                for (int j = 0; j < 4; ++j)
                    acc[i][j] += av[i] * bv[j];
        }
    }
    #pragma unroll
    for (int i = 0; i < 8; ++i) {
        int o = o0 + to * 8 + i;
        float bb = bias ? bias[o] : 0.0f;
        float4 r;
        r.x = acc[i][0] + bb; r.y = acc[i][1] + bb;
        r.z = acc[i][2] + bb; r.w = acc[i][3] + bb;
        *(float4*)&Y[(size_t)o * ldy + ym0 + tm * 4] = r;
    }
}

// ---- V branch: numpy SSE2-SOP GEMM + unfused np BN/LIF -> bf16 spikes ------
// Per element: 4 stripe accumulators (lane = c&3), c ascending, products
// mul+add separately rounded; reduce (s0+s2)+(s1+s3); unfused BN/LIF.
__global__ __launch_bounds__(256) void k_gemm_vsse(const float* __restrict__ W,
                                                   const float* __restrict__ X,
                                                   const float* __restrict__ bnp,
                                                   __hip_bfloat16* __restrict__ Y)
{
    __shared__ float sW[96][17];
    __shared__ float sX[96][65];
    int m0 = blockIdx.x * 64;
    int o0 = blockIdx.y * 16;
    int tid = threadIdx.x;
    int to = tid >> 4, tm = tid & 15;

    float acc[4][4];    // [stripe][elem]
    #pragma unroll
    for (int s = 0; s < 4; ++s)
        #pragma unroll
        for (int e = 0; e < 4; ++e) acc[s][e] = 0.0f;

    for (int blk = 0; blk < 4; ++blk) {
        int k0 = blk * 96;
        __syncthreads();
        for (int i = tid; i < 16 * 96; i += 256) {
            int o = i / 96, k = i - o * 96;
            sW[k][o] = W[(size_t)(o0 + o) * Cv + k0 + k];
        }
        for (int i = tid; i < 96 * 64; i += 256) {
            int k = i >> 6, m = i & 63;
            sX[k][m] = X[(size_t)(k0 + k) * Mv + m0 + m];
        }
        __syncthreads();
        for (int j = 0; j < 24; ++j) {          // c ascending, stripes = c&3
            #pragma unroll
            for (int s = 0; s < 4; ++s) {
                int kk = j * 4 + s;
                float w = sW[kk][to];
                #pragma unroll
                for (int e = 0; e < 4; ++e) {
                    float p = __fmul_rn(w, sX[kk][tm * 4 + e]);
                    acc[s][e] = __fadd_rn(acc[s][e], p);
                }
            }
        }
    }

    int o = o0 + to;
    // numpy ufunc flavor: inv = 1/sqrt(var+eps); sc = gamma*inv; unfused.
    float inv = __fdiv_rn(1.0f, __fsqrt_rn(__fadd_rn(bnp[3*Cv + o], 1e-5f)));
    float sc  = __fmul_rn(bnp[o], inv);
    float mu  = bnp[2*Cv + o];
    float be  = bnp[Cv + o];
    float mem = 0.0f;
    ushort4 pk;
    unsigned short* pks = (unsigned short*)&pk;
    #pragma unroll
    for (int e = 0; e < 4; ++e) {   // e = timestep t
        // SSE2 npyv_sum_f32 tree: (L0+L2) + (L1+L3)
        float tot = __fadd_rn(__fadd_rn(acc[0][e], acc[2][e]),
                              __fadd_rn(acc[1][e], acc[3][e]));
        float bn = __fadd_rn(__fmul_rn(__fsub_rn(tot, mu), sc), be);
        mem = __fadd_rn(mem, __fmul_rn(__fsub_rn(bn, mem), 0.5f));
        int s = (mem > 1.0f);
        mem = s ? 0.0f : mem;
        pks[e] = s ? 0x3F80 : 0;
    }
    *(ushort4*)((unsigned short*)Y + (size_t)o * Mv + m0 + tm * 4) = pk;
}

// ---- BN + LIF(thr=1) -> bf16 spikes (r4 flavor; q/k branches) --------------
__global__ __launch_bounds__(256) void k_bnlif_spike(const float* __restrict__ y,
                                                     const float* __restrict__ bnp,
                                                     __hip_bfloat16* __restrict__ sp)
{
    int idx = blockIdx.x * 256 + threadIdx.x;
    int c = idx / Zv;
    float gamma = bnp[c], beta = bnp[Cv+c], mean = bnp[2*Cv+c], var = bnp[3*Cv+c];
    float scale = gamma / sqrtf(var + 1e-5f);
    size_t base = (size_t)idx * 4;
    float4 yv = *(const float4*)(y + base);
    float xi[4] = {yv.x, yv.y, yv.z, yv.w};
    ushort4 pk;
    unsigned short* pks = (unsigned short*)&pk;
    float mem = 0.f;
    #pragma unroll
    for (int t = 0; t < 4; ++t) {
        float xv = (xi[t] - mean) * scale + beta;
        mem = mem + (xv - mem) * 0.5f;
        float s = (mem > 1.0f) ? 1.0f : 0.0f;
        mem *= (1.0f - s);
        pks[t] = (s > 0.5f) ? 0x3F80 : 0;
    }
    *(ushort4*)((unsigned short*)sp + base) = pk;
}

// ---- attention per (h, tbl): popcount QK^T, exact fp32 PV ------------------
__global__ __launch_bounds__(256) void k_attn(const __hip_bfloat16* __restrict__ qs,
                                              const __hip_bfloat16* __restrict__ ks,
                                              const __hip_bfloat16* __restrict__ vs,
                                              float* __restrict__ o_chan,
                                              float* __restrict__ v_out)
{
    int h = blockIdx.x, tbl = blockIdx.y;
    int t = tbl >> 5, b = tbl & 31;
    int tid = threadIdx.x;
    __shared__ unsigned kmask[196];
    __shared__ float vf[196][36];
    size_t chb  = (size_t)h * 32 * Mv;
    size_t colb = (size_t)b * Nv * 4 + t;

    for (int e = tid; e < Nv * 32; e += 256) {
        int dd = e / Nv, n = e - dd * Nv;
        vf[n][dd] = __bfloat162float(vs[chb + (size_t)dd * Mv + colb + (size_t)n * 4]);
    }
    unsigned qm = 0;
    if (tid < Nv) {
        unsigned km = 0;
        #pragma unroll
        for (int dd = 0; dd < 32; ++dd) {
            size_t off = chb + (size_t)dd * Mv + colb + (size_t)tid * 4;
            km |= (__bfloat162float(ks[off]) > 0.5f ? 1u : 0u) << dd;
            qm |= (__bfloat162float(qs[off]) > 0.5f ? 1u : 0u) << dd;
        }
        kmask[tid] = km;
    }
    __syncthreads();
    for (int e = tid; e < Nv * 32; e += 256) {
        int n = e >> 5, dd = e & 31;
        v_out[((size_t)(tbl * 12 + h) * Nv + n) * 32 + dd] = vf[n][dd];
    }
    if (tid < Nv) {
        float acc[32] = {};
        for (int nk = 0; nk < Nv; ++nk) {
            float a = (float)__popc(qm & kmask[nk]) * 0.125f;   // exact
            #pragma unroll
            for (int dd = 0; dd < 32; ++dd) acc[dd] += a * vf[nk][dd];
        }
        #pragma unroll
        for (int dd = 0; dd < 32; ++dd)
            o_chan[chb + (size_t)dd * Mv + colb + (size_t)tid * 4] = acc[dd];
    }
}

// ---- attn LIF (thr=0.5): exact (dyadic grid) -------------------------------
__global__ __launch_bounds__(256) void k_attnlif(float* __restrict__ o)
{
    int idx = blockIdx.x * 256 + threadIdx.x;
    size_t base = (size_t)idx * 4;
    float4 v = *(const float4*)(o + base);
    float xi[4] = {v.x, v.y, v.z, v.w};
    float s4[4];
    float mem = 0.f;
    #pragma unroll
    for (int t = 0; t < 4; ++t) {
        mem = mem + (xi[t] - mem) * 0.5f;
        s4[t] = (mem > 0.5f) ? 1.0f : 0.0f;
        mem *= (1.0f - s4[t]);
    }
    float4 r; r.x = s4[0]; r.y = s4[1]; r.z = s4[2]; r.w = s4[3];
    *(float4*)(o + base) = r;
}

// ---- proj BN+LIF(thr=1): x1 += s and s_proj (bf16) -------------------------
__global__ __launch_bounds__(256) void k_resid(const float* __restrict__ p,
                                               const float* __restrict__ bnp,
                                               float* __restrict__ x1,
                                               __hip_bfloat16* __restrict__ s_proj)
{
    int idx = blockIdx.x * 256 + threadIdx.x;
    int c = idx / Zv;
    float gamma = bnp[c], beta = bnp[Cv+c], mean = bnp[2*Cv+c], var = bnp[3*Cv+c];
    float scale = gamma / sqrtf(var + 1e-5f);
    size_t base = (size_t)idx * 4;
    float4 pv = *(const float4*)(p + base);
    float xi[4] = {pv.x, pv.y, pv.z, pv.w};
    float4 xv = *(const float4*)(x1 + base);
    float xr[4] = {xv.x, xv.y, xv.z, xv.w};
    ushort4 pk;
    unsigned short* pks = (unsigned short*)&pk;
    float mem = 0.f;
    #pragma unroll
    for (int t = 0; t < 4; ++t) {
        float bnv = (xi[t] - mean) * scale + beta;
        mem = mem + (bnv - mem) * 0.5f;
        float s = (mem > 1.0f) ? 1.0f : 0.0f;
        mem *= (1.0f - s);
        xr[t] += s;
        pks[t] = (s > 0.5f) ? 0x3F80 : 0;
    }
    float4 r; r.x = xr[0]; r.y = xr[1]; r.z = xr[2]; r.w = xr[3];
    *(float4*)(x1 + base) = r;
    *(ushort4*)((unsigned short*)s_proj + base) = pk;
}

// ---- fc1 BN+LIF(thr=1) in place on chunk buffer [1536][12544] --------------
__global__ __launch_bounds__(256) void k_bnlif_h(float* __restrict__ hbuf,
                                                 const float* __restrict__ bnp)
{
    int idx = blockIdx.x * 256 + threadIdx.x;
    int o = idx / UC;
    float gamma = bnp[o], beta = bnp[HIDv+o], mean = bnp[2*HIDv+o], var = bnp[3*HIDv+o];
    float scale = gamma / sqrtf(var + 1e-5f);
    size_t base = (size_t)idx * 4;
    float4 hv = *(const float4*)(hbuf + base);
    float xi[4] = {hv.x, hv.y, hv.z, hv.w};
    float s4[4];
    float mem = 0.f;
    #pragma unroll
    for (int t = 0; t < 4; ++t) {
        float bnv = (xi[t] - mean) * scale + beta;
        mem = mem + (bnv - mem) * 0.5f;
        s4[t] = (mem > 1.0f) ? 1.0f : 0.0f;
        mem *= (1.0f - s4[t]);
    }
    float4 r; r.x = s4[0]; r.y = s4[1]; r.z = s4[2]; r.w = s4[3];
    *(float4*)(hbuf + base) = r;
}

// ---- fc2 BN+LIF + out = x(direct) + s_proj + s_fc2, FP32 -------------------
__global__ __launch_bounds__(256) void k_final(const float* __restrict__ h2,
                                               const float* __restrict__ bnp,
                                               const float* __restrict__ x,
                                               const __hip_bfloat16* __restrict__ s_proj,
                                               float* __restrict__ out,
                                               int b0)
{
    int idx = blockIdx.x * 256 + threadIdx.x;
    int c = idx / UC;
    int u = idx - c * UC;
    int bp = u / Nv, n = u - bp * Nv;
    int b = b0 + bp;
    float gamma = bnp[c], beta = bnp[Cv+c], mean = bnp[2*Cv+c], var = bnp[3*Cv+c];
    float scale = gamma / sqrtf(var + 1e-5f);
    float4 hv = *(const float4*)(h2 + (size_t)c * CHUNK + (size_t)u * 4);
    float xi[4] = {hv.x, hv.y, hv.z, hv.w};
    ushort4 sp4 = *(const ushort4*)((const unsigned short*)s_proj +
                                    (size_t)c * Mv + ((size_t)b * Nv + n) * 4);
    unsigned short* sps = (unsigned short*)&sp4;
    float mem = 0.f;
    #pragma unroll
    for (int t = 0; t < 4; ++t) {
        float bnv = (xi[t] - mean) * scale + beta;
        mem = mem + (bnv - mem) * 0.5f;
        float s = (mem > 1.0f) ? 1.0f : 0.0f;
        mem *= (1.0f - s);
        size_t oidx = ((size_t)(t * Bv + b) * Cv + c) * Nv + n;
        float sproj = sps[t] ? 1.0f : 0.0f;
        out[oidx] = x[oidx] + sproj + s;
    }
}

extern "C" void kernel_launch(void* const* d_in, const int* in_sizes, int n_in,
                              void* d_out, int out_size, void* d_ws, size_t ws_size,
                              hipStream_t stream)
{
    const float* x       = (const float*)d_in[0];
    const float* qkvp_w  = (const float*)d_in[1];
    const float* qkvp_bn = (const float*)d_in[2];
    const float* fc1_w   = (const float*)d_in[3];
    const float* fc1_b   = (const float*)d_in[4];
    const float* fc1_bn  = (const float*)d_in[5];
    const float* fc2_w   = (const float*)d_in[6];
    const float* fc2_b   = (const float*)d_in[7];
    const float* fc2_bn  = (const float*)d_in[8];

    float* out1 = (float*)d_out;                    // x_out fp32
    float* out2 = out1 + (size_t)TBv * Cv * Nv;     // v fp32

    float* wsf = (float*)d_ws;
    const size_t S = (size_t)Cv * Mv;
    if (ws_size < 4 * S * sizeof(float)) return;

    float* xp   = wsf;                                  // xp -> x1
    float* ybuf = wsf + S;                              // pre-BN y / attn o
    __hip_bfloat16* qs = (__hip_bfloat16*)(wsf + 2*S);
    __hip_bfloat16* ks = qs + S;
    __hip_bfloat16* vs = qs + 2*S;
    float* pbuf  = wsf + 2*S;                           // proj pre-BN (q/k dead)
    float* hbuf  = wsf + S;                             // fc1 out
    float* h2buf = wsf + 3*S;                           // fc2 out (vs dead)
    __hip_bfloat16* s_proj = (__hip_bfloat16*)(wsf + 3*S + S/2);

    k_transpose_in<<<37632, 256, 0, stream>>>(x, xp);

    // q, k: r4 fp32 pipeline (proven). v: SSE2-SOP numpy einsum flavor.
    for (int br = 0; br < 2; ++br) {
        k_gemm<<<dim3(392, 3), 256, 0, stream>>>(qkvp_w + (size_t)br*Cv*Cv, xp, ybuf,
                                                 Cv, Mv, Mv, nullptr, 0);
        __hip_bfloat16* sp = (br == 0) ? qs : ks;
        k_bnlif_spike<<<9408, 256, 0, stream>>>(ybuf, qkvp_bn + (size_t)br*4*Cv, sp);
    }
    k_gemm_vsse<<<dim3(392, 24), 256, 0, stream>>>(qkvp_w + (size_t)2*Cv*Cv, xp,
                                                   qkvp_bn + (size_t)2*4*Cv, vs);

    k_attn<<<dim3(12, 128), 256, 0, stream>>>(qs, ks, vs, ybuf, out2);
    k_attnlif<<<9408, 256, 0, stream>>>(ybuf);

    k_gemm<<<dim3(392, 3), 256, 0, stream>>>(qkvp_w + (size_t)3*Cv*Cv, ybuf, pbuf,
                                             Cv, Mv, Mv, nullptr, 0);
    k_resid<<<9408, 256, 0, stream>>>(pbuf, qkvp_bn + (size_t)3*4*Cv, xp, s_proj);

    for (int ch = 0; ch < 2; ++ch) {
        k_gemm<<<dim3(196, 12), 256, 0, stream>>>(fc1_w, xp, hbuf,
                                                  Cv, Mv, CHUNK, fc1_b, ch * CHUNK);
        k_bnlif_h<<<18816, 256, 0, stream>>>(hbuf, fc1_bn);
        k_gemm<<<dim3(196, 3), 256, 0, stream>>>(fc2_w, hbuf, h2buf,
                                                 HIDv, CHUNK, CHUNK, fc2_b, 0);
        k_final<<<4704, 256, 0, stream>>>(h2buf, fc2_bn, x, s_proj, out1, ch * 16);
    }
}

// Round 12
// 1631.315 us; speedup vs baseline: 1.1500x; 1.1500x over previous
//
#include <hip/hip_runtime.h>
#include <hip/hip_bf16.h>

// Spiking transformer block (Spikformer SSA) on MI355X.
// Layout: [channel][m], m = (b*196+n)*4 + t (time innermost).
//
// CORRECTNESS CONTRACT (r11 PASSED, absmax 0.0 bitwise):
//  - v branch: numpy SSE2-SOP einsum flavor — 4 stripe accumulators (lane=c&3),
//    c ascending, separate __fmul_rn/__fadd_rn, reduce (s0+s2)+(s1+s3),
//    unfused __f*_rn BN/LIF.  - out0 branches: in-order ascending-k fp32 FMA
//    chain per element, zero-init.  - elementwise kernels byte-identical.
// Retiling is bitwise-safe (a chain depends only on its value sequence);
// MFMA / k-splitting / flavor changes are NOT.

#define Cv 384
#define Nv 196
#define Mv 25088        // 128*196 columns
#define HIDv 1536
#define Bv 32
#define Zv 6272         // z = b*196+n
#define TBv 128
#define CHUNK 12544     // Mv/2
#define UC 3136         // per-chunk u

// ---- transpose: xp[c*Mv + (b*196+n)*4 + t] = x[((t*32+b)*384+c)*196+n] ----
__global__ __launch_bounds__(256) void k_transpose_in(const float* __restrict__ x,
                                                      float* __restrict__ xp)
{
    int idx = blockIdx.x * 256 + threadIdx.x;
    int c   = idx / Mv;
    int rem = idx - c * Mv;
    int z = rem >> 2, t = rem & 3;
    int b = z / Nv, n = z - b * Nv;
    xp[idx] = x[((size_t)(t * Bv + b) * Cv + c) * Nv + n];
}

// ---- fp32 GEMM, 128x128 tile, 8x8 split microtile, in-order FMA chains -----
// Bitwise == r4 k_gemm per element: acc = fmaf(W[o][k], X[k][m], acc), k asc.
__global__ __launch_bounds__(256) void k_gemm2(const float* __restrict__ W,
                                               const float* __restrict__ X,
                                               float* __restrict__ Y,
                                               int K, int ldx, int ldy,
                                               const float* __restrict__ bias,
                                               int cb)
{
    __shared__ float sW[8][128];
    __shared__ float sX[8][128];
    int ym0 = blockIdx.x * 128;
    int m0  = cb + ym0;
    int o0  = blockIdx.y * 128;
    int tid = threadIdx.x;
    int wo = tid & 127, wh = tid >> 7;        // W stage: o row, k-half (4 k's)
    int xr = tid >> 5,  xc = (tid & 31) * 4;  // X stage: k row, float4 col
    int to = tid >> 4,  tm = tid & 15;        // microtile coords

    const float* Wp = W + (size_t)(o0 + wo) * K + wh * 4;
    const float* Xp = X + (size_t)xr * ldx + m0 + xc;

    float acc[8][8];
    #pragma unroll
    for (int i = 0; i < 8; ++i)
        #pragma unroll
        for (int j = 0; j < 8; ++j) acc[i][j] = 0.0f;

    for (int k0 = 0; k0 < K; k0 += 8) {
        float4 w4 = *(const float4*)(Wp + k0);
        float4 x4 = *(const float4*)(Xp + (size_t)k0 * ldx);
        __syncthreads();
        sW[wh*4+0][wo] = w4.x;
        sW[wh*4+1][wo] = w4.y;
        sW[wh*4+2][wo] = w4.z;
        sW[wh*4+3][wo] = w4.w;
        *(float4*)&sX[xr][xc] = x4;
        __syncthreads();
        #pragma unroll
        for (int kk = 0; kk < 8; ++kk) {
            float4 a0 = *(const float4*)&sW[kk][to*4];
            float4 a1 = *(const float4*)&sW[kk][64 + to*4];
            float4 b0 = *(const float4*)&sX[kk][tm*4];
            float4 b1 = *(const float4*)&sX[kk][64 + tm*4];
            float av[8] = {a0.x,a0.y,a0.z,a0.w,a1.x,a1.y,a1.z,a1.w};
            float bv[8] = {b0.x,b0.y,b0.z,b0.w,b1.x,b1.y,b1.z,b1.w};
            #pragma unroll
            for (int i = 0; i < 8; ++i)
                #pragma unroll
                for (int j = 0; j < 8; ++j)
                    acc[i][j] = fmaf(av[i], bv[j], acc[i][j]);
        }
    }
    #pragma unroll
    for (int i = 0; i < 8; ++i) {
        int oi = (i < 4) ? (to*4 + i) : (64 + to*4 + i - 4);
        int o  = o0 + oi;
        float bb = bias ? bias[o] : 0.0f;
        float4 r0, r1;
        r0.x = acc[i][0] + bb; r0.y = acc[i][1] + bb;
        r0.z = acc[i][2] + bb; r0.w = acc[i][3] + bb;
        r1.x = acc[i][4] + bb; r1.y = acc[i][5] + bb;
        r1.z = acc[i][6] + bb; r1.w = acc[i][7] + bb;
        *(float4*)&Y[(size_t)o * ldy + ym0 + tm*4]      = r0;
        *(float4*)&Y[(size_t)o * ldy + ym0 + 64 + tm*4] = r1;
    }
}

// ---- V branch: SSE2-SOP GEMM, 64x64 tile, 4o x 1site microtile -------------
// Bitwise == r11 k_gemm_vsse per element: 4 stripe chains (c asc, mul+add
// separate), reduce (s0+s2)+(s1+s3), unfused __f*_rn BN/LIF epilogue.
__global__ __launch_bounds__(256) void k_vsse2(const float* __restrict__ W,
                                               const float* __restrict__ X,
                                               const float* __restrict__ bnp,
                                               __hip_bfloat16* __restrict__ Y)
{
    __shared__ float sW[32][68];    // [kk][o], pad 68 keeps 16B align + 2-way
    __shared__ float sX[32][64];
    int m0 = blockIdx.x * 64;
    int o0 = blockIdx.y * 64;
    int tid = threadIdx.x;
    int to = tid >> 4, tm = tid & 15;

    float acc[4][4][4];     // [stripe][o'][e]
    #pragma unroll
    for (int s = 0; s < 4; ++s)
        #pragma unroll
        for (int op = 0; op < 4; ++op)
            #pragma unroll
            for (int e = 0; e < 4; ++e) acc[s][op][e] = 0.0f;

    int wq_o = tid >> 3, wq_c = tid & 7;      // W stage: 64 o x 8 float4-cols
    int xs_r = tid >> 3, xs_c = (tid & 7) * 8; // X stage: 32 rows x 2 float4

    for (int blk = 0; blk < 12; ++blk) {
        int k0 = blk * 32;
        __syncthreads();
        {   // stage W: sW[kk][o] = W[o0+o][k0+kk]
            float4 w4 = *(const float4*)(W + (size_t)(o0 + wq_o) * Cv + k0 + wq_c*4);
            sW[wq_c*4+0][wq_o] = w4.x;
            sW[wq_c*4+1][wq_o] = w4.y;
            sW[wq_c*4+2][wq_o] = w4.z;
            sW[wq_c*4+3][wq_o] = w4.w;
            float4 w5 = *(const float4*)(W + (size_t)(o0 + 32 + wq_o) * Cv + k0 + wq_c*4);
            sW[wq_c*4+0][32 + wq_o] = w5.x;
            sW[wq_c*4+1][32 + wq_o] = w5.y;
            sW[wq_c*4+2][32 + wq_o] = w5.z;
            sW[wq_c*4+3][32 + wq_o] = w5.w;
        }
        {   // stage X: sX[kk][m'] = X[k0+kk][m0+m']
            const float* Xp = X + (size_t)(k0 + xs_r) * Mv + m0 + xs_c;
            *(float4*)&sX[xs_r][xs_c]     = *(const float4*)(Xp);
            *(float4*)&sX[xs_r][xs_c + 4] = *(const float4*)(Xp + 4);
        }
        __syncthreads();
        #pragma unroll
        for (int j = 0; j < 8; ++j) {
            #pragma unroll
            for (int s = 0; s < 4; ++s) {
                int kk = j * 4 + s;             // c = k0 + j*4 + s  (stripe c&3)
                float4 w4 = *(const float4*)&sW[kk][to*4];
                float4 x4 = *(const float4*)&sX[kk][tm*4];
                float wv[4] = {w4.x, w4.y, w4.z, w4.w};
                float xv[4] = {x4.x, x4.y, x4.z, x4.w};
                #pragma unroll
                for (int op = 0; op < 4; ++op)
                    #pragma unroll
                    for (int e = 0; e < 4; ++e)
                        acc[s][op][e] = __fadd_rn(acc[s][op][e],
                                                  __fmul_rn(wv[op], xv[e]));
            }
        }
    }

    #pragma unroll
    for (int op = 0; op < 4; ++op) {
        int o = o0 + to*4 + op;
        float inv = __fdiv_rn(1.0f, __fsqrt_rn(__fadd_rn(bnp[3*Cv + o], 1e-5f)));
        float sc  = __fmul_rn(bnp[o], inv);
        float mu  = bnp[2*Cv + o];
        float be  = bnp[Cv + o];
        float mem = 0.0f;
        ushort4 pk;
        unsigned short* pks = (unsigned short*)&pk;
        #pragma unroll
        for (int e = 0; e < 4; ++e) {
            float tot = __fadd_rn(__fadd_rn(acc[0][op][e], acc[2][op][e]),
                                  __fadd_rn(acc[1][op][e], acc[3][op][e]));
            float bn = __fadd_rn(__fmul_rn(__fsub_rn(tot, mu), sc), be);
            mem = __fadd_rn(mem, __fmul_rn(__fsub_rn(bn, mem), 0.5f));
            int s = (mem > 1.0f);
            mem = s ? 0.0f : mem;
            pks[e] = s ? 0x3F80 : 0;
        }
        *(ushort4*)((unsigned short*)Y + (size_t)o * Mv + m0 + tm * 4) = pk;
    }
}

// ---- BN + LIF(thr=1) -> bf16 spikes (r4 flavor; q/k branches) --------------
__global__ __launch_bounds__(256) void k_bnlif_spike(const float* __restrict__ y,
                                                     const float* __restrict__ bnp,
                                                     __hip_bfloat16* __restrict__ sp)
{
    int idx = blockIdx.x * 256 + threadIdx.x;
    int c = idx / Zv;
    float gamma = bnp[c], beta = bnp[Cv+c], mean = bnp[2*Cv+c], var = bnp[3*Cv+c];
    float scale = gamma / sqrtf(var + 1e-5f);
    size_t base = (size_t)idx * 4;
    float4 yv = *(const float4*)(y + base);
    float xi[4] = {yv.x, yv.y, yv.z, yv.w};
    ushort4 pk;
    unsigned short* pks = (unsigned short*)&pk;
    float mem = 0.f;
    #pragma unroll
    for (int t = 0; t < 4; ++t) {
        float xv = (xi[t] - mean) * scale + beta;
        mem = mem + (xv - mem) * 0.5f;
        float s = (mem > 1.0f) ? 1.0f : 0.0f;
        mem *= (1.0f - s);
        pks[t] = (s > 0.5f) ? 0x3F80 : 0;
    }
    *(ushort4*)((unsigned short*)sp + base) = pk;
}

// ---- attention per (h, tbl): popcount QK^T, exact fp32 PV ------------------
__global__ __launch_bounds__(256) void k_attn(const __hip_bfloat16* __restrict__ qs,
                                              const __hip_bfloat16* __restrict__ ks,
                                              const __hip_bfloat16* __restrict__ vs,
                                              float* __restrict__ o_chan,
                                              float* __restrict__ v_out)
{
    int h = blockIdx.x, tbl = blockIdx.y;
    int t = tbl >> 5, b = tbl & 31;
    int tid = threadIdx.x;
    __shared__ unsigned kmask[196];
    __shared__ float vf[196][36];
    size_t chb  = (size_t)h * 32 * Mv;
    size_t colb = (size_t)b * Nv * 4 + t;

    for (int e = tid; e < Nv * 32; e += 256) {
        int dd = e / Nv, n = e - dd * Nv;
        vf[n][dd] = __bfloat162float(vs[chb + (size_t)dd * Mv + colb + (size_t)n * 4]);
    }
    unsigned qm = 0;
    if (tid < Nv) {
        unsigned km = 0;
        #pragma unroll
        for (int dd = 0; dd < 32; ++dd) {
            size_t off = chb + (size_t)dd * Mv + colb + (size_t)tid * 4;
            km |= (__bfloat162float(ks[off]) > 0.5f ? 1u : 0u) << dd;
            qm |= (__bfloat162float(qs[off]) > 0.5f ? 1u : 0u) << dd;
        }
        kmask[tid] = km;
    }
    __syncthreads();
    for (int e = tid; e < Nv * 32; e += 256) {
        int n = e >> 5, dd = e & 31;
        v_out[((size_t)(tbl * 12 + h) * Nv + n) * 32 + dd] = vf[n][dd];
    }
    if (tid < Nv) {
        float acc[32] = {};
        for (int nk = 0; nk < Nv; ++nk) {
            float a = (float)__popc(qm & kmask[nk]) * 0.125f;   // exact
            #pragma unroll
            for (int dd = 0; dd < 32; ++dd) acc[dd] += a * vf[nk][dd];
        }
        #pragma unroll
        for (int dd = 0; dd < 32; ++dd)
            o_chan[chb + (size_t)dd * Mv + colb + (size_t)tid * 4] = acc[dd];
    }
}

// ---- attn LIF (thr=0.5): exact (dyadic grid) -------------------------------
__global__ __launch_bounds__(256) void k_attnlif(float* __restrict__ o)
{
    int idx = blockIdx.x * 256 + threadIdx.x;
    size_t base = (size_t)idx * 4;
    float4 v = *(const float4*)(o + base);
    float xi[4] = {v.x, v.y, v.z, v.w};
    float s4[4];
    float mem = 0.f;
    #pragma unroll
    for (int t = 0; t < 4; ++t) {
        mem = mem + (xi[t] - mem) * 0.5f;
        s4[t] = (mem > 0.5f) ? 1.0f : 0.0f;
        mem *= (1.0f - s4[t]);
    }
    float4 r; r.x = s4[0]; r.y = s4[1]; r.z = s4[2]; r.w = s4[3];
    *(float4*)(o + base) = r;
}

// ---- proj BN+LIF(thr=1): x1 += s and s_proj (bf16) -------------------------
__global__ __launch_bounds__(256) void k_resid(const float* __restrict__ p,
                                               const float* __restrict__ bnp,
                                               float* __restrict__ x1,
                                               __hip_bfloat16* __restrict__ s_proj)
{
    int idx = blockIdx.x * 256 + threadIdx.x;
    int c = idx / Zv;
    float gamma = bnp[c], beta = bnp[Cv+c], mean = bnp[2*Cv+c], var = bnp[3*Cv+c];
    float scale = gamma / sqrtf(var + 1e-5f);
    size_t base = (size_t)idx * 4;
    float4 pv = *(const float4*)(p + base);
    float xi[4] = {pv.x, pv.y, pv.z, pv.w};
    float4 xv = *(const float4*)(x1 + base);
    float xr[4] = {xv.x, xv.y, xv.z, xv.w};
    ushort4 pk;
    unsigned short* pks = (unsigned short*)&pk;
    float mem = 0.f;
    #pragma unroll
    for (int t = 0; t < 4; ++t) {
        float bnv = (xi[t] - mean) * scale + beta;
        mem = mem + (bnv - mem) * 0.5f;
        float s = (mem > 1.0f) ? 1.0f : 0.0f;
        mem *= (1.0f - s);
        xr[t] += s;
        pks[t] = (s > 0.5f) ? 0x3F80 : 0;
    }
    float4 r; r.x = xr[0]; r.y = xr[1]; r.z = xr[2]; r.w = xr[3];
    *(float4*)(x1 + base) = r;
    *(ushort4*)((unsigned short*)s_proj + base) = pk;
}

// ---- fc1 BN+LIF(thr=1) in place on chunk buffer [1536][12544] --------------
__global__ __launch_bounds__(256) void k_bnlif_h(float* __restrict__ hbuf,
                                                 const float* __restrict__ bnp)
{
    int idx = blockIdx.x * 256 + threadIdx.x;
    int o = idx / UC;
    float gamma = bnp[o], beta = bnp[HIDv+o], mean = bnp[2*HIDv+o], var = bnp[3*HIDv+o];
    float scale = gamma / sqrtf(var + 1e-5f);
    size_t base = (size_t)idx * 4;
    float4 hv = *(const float4*)(hbuf + base);
    float xi[4] = {hv.x, hv.y, hv.z, hv.w};
    float s4[4];
    float mem = 0.f;
    #pragma unroll
    for (int t = 0; t < 4; ++t) {
        float bnv = (xi[t] - mean) * scale + beta;
        mem = mem + (bnv - mem) * 0.5f;
        s4[t] = (mem > 1.0f) ? 1.0f : 0.0f;
        mem *= (1.0f - s4[t]);
    }
    float4 r; r.x = s4[0]; r.y = s4[1]; r.z = s4[2]; r.w = s4[3];
    *(float4*)(hbuf + base) = r;
}

// ---- fc2 BN+LIF + out = x(direct) + s_proj + s_fc2, FP32 -------------------
__global__ __launch_bounds__(256) void k_final(const float* __restrict__ h2,
                                               const float* __restrict__ bnp,
                                               const float* __restrict__ x,
                                               const __hip_bfloat16* __restrict__ s_proj,
                                               float* __restrict__ out,
                                               int b0)
{
    int idx = blockIdx.x * 256 + threadIdx.x;
    int c = idx / UC;
    int u = idx - c * UC;
    int bp = u / Nv, n = u - bp * Nv;
    int b = b0 + bp;
    float gamma = bnp[c], beta = bnp[Cv+c], mean = bnp[2*Cv+c], var = bnp[3*Cv+c];
    float scale = gamma / sqrtf(var + 1e-5f);
    float4 hv = *(const float4*)(h2 + (size_t)c * CHUNK + (size_t)u * 4);
    float xi[4] = {hv.x, hv.y, hv.z, hv.w};
    ushort4 sp4 = *(const ushort4*)((const unsigned short*)s_proj +
                                    (size_t)c * Mv + ((size_t)b * Nv + n) * 4);
    unsigned short* sps = (unsigned short*)&sp4;
    float mem = 0.f;
    #pragma unroll
    for (int t = 0; t < 4; ++t) {
        float bnv = (xi[t] - mean) * scale + beta;
        mem = mem + (bnv - mem) * 0.5f;
        float s = (mem > 1.0f) ? 1.0f : 0.0f;
        mem *= (1.0f - s);
        size_t oidx = ((size_t)(t * Bv + b) * Cv + c) * Nv + n;
        float sproj = sps[t] ? 1.0f : 0.0f;
        out[oidx] = x[oidx] + sproj + s;
    }
}

extern "C" void kernel_launch(void* const* d_in, const int* in_sizes, int n_in,
                              void* d_out, int out_size, void* d_ws, size_t ws_size,
                              hipStream_t stream)
{
    const float* x       = (const float*)d_in[0];
    const float* qkvp_w  = (const float*)d_in[1];
    const float* qkvp_bn = (const float*)d_in[2];
    const float* fc1_w   = (const float*)d_in[3];
    const float* fc1_b   = (const float*)d_in[4];
    const float* fc1_bn  = (const float*)d_in[5];
    const float* fc2_w   = (const float*)d_in[6];
    const float* fc2_b   = (const float*)d_in[7];
    const float* fc2_bn  = (const float*)d_in[8];

    float* out1 = (float*)d_out;                    // x_out fp32
    float* out2 = out1 + (size_t)TBv * Cv * Nv;     // v fp32

    float* wsf = (float*)d_ws;
    const size_t S = (size_t)Cv * Mv;
    if (ws_size < 4 * S * sizeof(float)) return;

    float* xp   = wsf;                                  // xp -> x1
    float* ybuf = wsf + S;                              // pre-BN y / attn o
    __hip_bfloat16* qs = (__hip_bfloat16*)(wsf + 2*S);
    __hip_bfloat16* ks = qs + S;
    __hip_bfloat16* vs = qs + 2*S;
    float* pbuf  = wsf + 2*S;                           // proj pre-BN (q/k dead)
    float* hbuf  = wsf + S;                             // fc1 out
    float* h2buf = wsf + 3*S;                           // fc2 out (vs dead)
    __hip_bfloat16* s_proj = (__hip_bfloat16*)(wsf + 3*S + S/2);

    k_transpose_in<<<37632, 256, 0, stream>>>(x, xp);

    // q, k: in-order FMA GEMM (retiled, bitwise == r4) + proven BN/LIF
    for (int br = 0; br < 2; ++br) {
        k_gemm2<<<dim3(196, 3), 256, 0, stream>>>(qkvp_w + (size_t)br*Cv*Cv, xp, ybuf,
                                                  Cv, Mv, Mv, nullptr, 0);
        __hip_bfloat16* sp = (br == 0) ? qs : ks;
        k_bnlif_spike<<<9408, 256, 0, stream>>>(ybuf, qkvp_bn + (size_t)br*4*Cv, sp);
    }
    // v: SSE2-SOP flavor (retiled, bitwise == r11)
    k_vsse2<<<dim3(392, 6), 256, 0, stream>>>(qkvp_w + (size_t)2*Cv*Cv, xp,
                                              qkvp_bn + (size_t)2*4*Cv, vs);

    k_attn<<<dim3(12, 128), 256, 0, stream>>>(qs, ks, vs, ybuf, out2);
    k_attnlif<<<9408, 256, 0, stream>>>(ybuf);

    k_gemm2<<<dim3(196, 3), 256, 0, stream>>>(qkvp_w + (size_t)3*Cv*Cv, ybuf, pbuf,
                                              Cv, Mv, Mv, nullptr, 0);
    k_resid<<<9408, 256, 0, stream>>>(pbuf, qkvp_bn + (size_t)3*4*Cv, xp, s_proj);

    for (int ch = 0; ch < 2; ++ch) {
        k_gemm2<<<dim3(98, 12), 256, 0, stream>>>(fc1_w, xp, hbuf,
                                                  Cv, Mv, CHUNK, fc1_b, ch * CHUNK);
        k_bnlif_h<<<18816, 256, 0, stream>>>(hbuf, fc1_bn);
        k_gemm2<<<dim3(98, 3), 256, 0, stream>>>(fc2_w, hbuf, h2buf,
                                                 HIDv, CHUNK, CHUNK, fc2_b, 0);
        k_final<<<4704, 256, 0, stream>>>(h2buf, fc2_bn, x, s_proj, out1, ch * 16);
    }
}